// Round 2
// baseline (539.818 us; speedup 1.0000x reference)
//
#include <hip/hip_runtime.h>

// PowerSpectrum: values[S,N,L,M,Q] -> out[S,N,L*Q*Q]
// out[s,n,l,q,p] = (1/sqrt(2l+1)) * sum_{m<2l+1} v[s,n,l,m,q] * v[s,n,l,m,p]
// S=4, N=2000, L=4, M=7, Q=64. Write-BW bound (524 MB out, 57 MB in).
//
// R2: each thread owns a 4x4 output tile -> per m just TWO ds_read_b128
// (a-quad + b-quad), 14 total vs R1's 56 LDS reads. Invalid m-rows are
// zeroed at staging so the m-loop is fully unrolled (no dynamic trip).

#define PS_S 4
#define PS_N 2000
#define PS_L 4
#define PS_M 7
#define PS_Q 64

__device__ __forceinline__ void fma4(float4& acc, float a, const float4& b) {
    acc.x += a * b.x;
    acc.y += a * b.y;
    acc.z += a * b.z;
    acc.w += a * b.w;
}

__global__ __launch_bounds__(256) void PowerSpectrum_kernel(
    const float* __restrict__ values, float* __restrict__ out) {
    // one block per (s, n, l); bid = ((s*N + n)*L + l)
    const int bid = blockIdx.x;
    const int l = bid & (PS_L - 1);              // L == 4
    const int meff = 2 * l + 1;                  // wave-uniform
    const float cg = rsqrtf((float)meff);
    const float* __restrict__ vin = values + (size_t)bid * (PS_M * PS_Q);
    float* __restrict__ o = out + (size_t)bid * (PS_Q * PS_Q);

    __shared__ float sv[PS_M][PS_Q];             // 1792 B

    const int t = threadIdx.x;
    // stage V tile (448 floats = 112 float4), zero-masking rows m >= 2l+1
    // so the compute loop can be a full 7-iteration unroll.
    if (t < (PS_M * PS_Q) / 4) {
        float4 x = ((const float4*)vin)[t];
        const int m = t >> 4;                    // 16 float4 per m-row
        if (m >= meff) x = make_float4(0.f, 0.f, 0.f, 0.f);
        ((float4*)&sv[0][0])[t] = x;
    }
    __syncthreads();

    const int p  = (t & 15) * 4;                 // column base of 4x4 tile
    const int q0 = (t >> 4) * 4;                 // row base of 4x4 tile

    float4 acc0 = make_float4(0.f, 0.f, 0.f, 0.f);
    float4 acc1 = make_float4(0.f, 0.f, 0.f, 0.f);
    float4 acc2 = make_float4(0.f, 0.f, 0.f, 0.f);
    float4 acc3 = make_float4(0.f, 0.f, 0.f, 0.f);

    #pragma unroll
    for (int m = 0; m < PS_M; ++m) {
        const float4 a = *(const float4*)&sv[m][q0];  // rows q0..q0+3
        const float4 b = *(const float4*)&sv[m][p];   // cols p..p+3
        fma4(acc0, a.x, b);
        fma4(acc1, a.y, b);
        fma4(acc2, a.z, b);
        fma4(acc3, a.w, b);
    }

    acc0.x *= cg; acc0.y *= cg; acc0.z *= cg; acc0.w *= cg;
    acc1.x *= cg; acc1.y *= cg; acc1.z *= cg; acc1.w *= cg;
    acc2.x *= cg; acc2.y *= cg; acc2.z *= cg; acc2.w *= cg;
    acc3.x *= cg; acc3.y *= cg; acc3.z *= cg; acc3.w *= cg;

    // each 16-lane group stores a contiguous 256 B run per row -> coalesced
    *(float4*)&o[(q0 + 0) * PS_Q + p] = acc0;
    *(float4*)&o[(q0 + 1) * PS_Q + p] = acc1;
    *(float4*)&o[(q0 + 2) * PS_Q + p] = acc2;
    *(float4*)&o[(q0 + 3) * PS_Q + p] = acc3;
}

extern "C" void kernel_launch(void* const* d_in, const int* in_sizes, int n_in,
                              void* d_out, int out_size, void* d_ws, size_t ws_size,
                              hipStream_t stream) {
    const float* values = (const float*)d_in[0];
    float* out = (float*)d_out;
    const int n_blocks = PS_S * PS_N * PS_L;     // 32000
    PowerSpectrum_kernel<<<n_blocks, 256, 0, stream>>>(values, out);
}